// Round 4
// baseline (254.591 us; speedup 1.0000x reference)
//
#include <hip/hip_runtime.h>
#include <math.h>

#define NB 4096
#define PAD 2048
#define BLOCK 512
#define V4 (NB / 4 / BLOCK)   // 2 float4 chunks per thread per row
#define ROWS 4
#define PBLOCK 256

__device__ __forceinline__ int mirror_idx(int i) {
    // valid for i in [-PAD, NB+PAD-2]; single reflection
    i = ::abs(i);
    return (i < NB) ? i : (2 * (NB - 1) - i);
}

// Barrier that waits only on LDS ops (lgkmcnt), leaving global loads/stores
// (vmcnt) in flight. __syncthreads() would drain vmcnt(0) (workgroup fence),
// killing the cross-row prefetch pipeline.
__device__ __forceinline__ void lds_barrier() {
    asm volatile("s_waitcnt lgkmcnt(0)\n\ts_barrier" ::: "memory");
}

// ws layout: p[0..NB), d[NB..2NB) = lsp - lsn, ws[2NB] = sum(lsn)
__global__ void fbmp_precompute(const float* __restrict__ logits, float* __restrict__ ws) {
    __shared__ float sred[PBLOCK / 64];
    float lsnsum = 0.0f;
    for (int j = threadIdx.x; j < NB; j += PBLOCK) {
        float x = logits[j];
        double xd = (double)x;
        // p formula bit-matched the reference in rounds 1-3 (absmax 0.0) -- do not touch
        float e = (float)exp(-xd);
        float p = 1.0f / (1.0f + e);
        float lsp = (float)(-log1p(exp(-xd)));  // log_sigmoid(x)
        float lsn = (float)(-log1p(exp(xd)));   // log_sigmoid(-x)
        ws[j] = p;
        ws[NB + j] = lsp - lsn;
        lsnsum += lsn;
    }
    #pragma unroll
    for (int off = 32; off > 0; off >>= 1)
        lsnsum += __shfl_down(lsnsum, off, 64);
    const int lane = threadIdx.x & 63;
    const int wid  = threadIdx.x >> 6;
    if (lane == 0) sred[wid] = lsnsum;
    __syncthreads();
    if (threadIdx.x == 0) {
        float t = 0.0f;
        #pragma unroll
        for (int w = 0; w < PBLOCK / 64; ++w) t += sred[w];
        ws[2 * NB] = t;
    }
}

__global__ __launch_bounds__(BLOCK, 8) void fbmp_main(
    const float* __restrict__ u, const int* __restrict__ shift,
    const float* __restrict__ ws,
    float* __restrict__ masks, float* __restrict__ logp)
{
    __shared__ float sg[2][NB];              // double-buffered grid bits
    __shared__ float sred[ROWS][BLOCK / 64];

    const int b = blockIdx.x;
    const int t = threadIdx.x;
    const int row0 = b * ROWS;

    // tables: once per block, live in registers for all ROWS rows
    const float4* __restrict__ p4 = (const float4*)ws;
    const float4* __restrict__ d4 = (const float4*)(ws + NB);
    float4 pv[V4], dv[V4];
    #pragma unroll
    for (int i = 0; i < V4; ++i) pv[i] = p4[t + i * BLOCK];
    #pragma unroll
    for (int i = 0; i < V4; ++i) dv[i] = d4[t + i * BLOCK];
    const float base = ws[2 * NB];

    // prologue: row 0 u loads
    float4 ucur[V4], unext[V4];
    {
        const float4* __restrict__ u0 = (const float4*)(u + (size_t)row0 * NB);
        #pragma unroll
        for (int i = 0; i < V4; ++i) ucur[i] = u0[t + i * BLOCK];
    }

    #pragma unroll
    for (int r = 0; r < ROWS; ++r) {
        // issue next row's loads FIRST -- they stay in flight across the
        // lgkm-only barrier below
        if (r + 1 < ROWS) {
            const float4* __restrict__ un =
                (const float4*)(u + (size_t)(row0 + r + 1) * NB);
            #pragma unroll
            for (int i = 0; i < V4; ++i) unext[i] = un[t + i * BLOCK];
        }
        const int s = shift[row0 + r] - PAD;  // issued early, used after barrier

        // compute grid bits + acc (same order as R3), write LDS buf[r&1]
        float* __restrict__ buf = sg[r & 1];
        float acc = 0.0f;
        #pragma unroll
        for (int i = 0; i < V4; ++i) {
            bool c0 = ucur[i].x < pv[i].x;
            bool c1 = ucur[i].y < pv[i].y;
            bool c2 = ucur[i].z < pv[i].z;
            bool c3 = ucur[i].w < pv[i].w;
            acc += (c0 ? dv[i].x : 0.0f) + (c1 ? dv[i].y : 0.0f)
                 + (c2 ? dv[i].z : 0.0f) + (c3 ? dv[i].w : 0.0f);
            float4 g;
            g.x = c0 ? 1.0f : 0.0f;
            g.y = c1 ? 1.0f : 0.0f;
            g.z = c2 ? 1.0f : 0.0f;
            g.w = c3 ? 1.0f : 0.0f;
            ((float4*)buf)[t + i * BLOCK] = g;
        }

        // per-row wave reduction; sred write drains at the barrier too
        #pragma unroll
        for (int off = 32; off > 0; off >>= 1)
            acc += __shfl_down(acc, off, 64);
        if ((t & 63) == 0) sred[r][t >> 6] = acc;

        lds_barrier();

        // reflect-shift gather from LDS, aligned float4 stores (stores stay
        // in flight past the next row's barrier)
        float4* __restrict__ m4 = (float4*)(masks + (size_t)(row0 + r) * NB);
        #pragma unroll
        for (int i = 0; i < V4; ++i) {
            const int k = 4 * (t + i * BLOCK) + s;
            float4 o;
            o.x = buf[mirror_idx(k + 0)];
            o.y = buf[mirror_idx(k + 1)];
            o.z = buf[mirror_idx(k + 2)];
            o.w = buf[mirror_idx(k + 3)];
            m4[t + i * BLOCK] = o;
        }

        #pragma unroll
        for (int i = 0; i < V4; ++i) ucur[i] = unext[i];
    }

    // all sred[r] writes precede the final lds_barrier -> visible here
    if (t == 0) {
        #pragma unroll
        for (int r = 0; r < ROWS; ++r) {
            float tot = 0.0f;
            #pragma unroll
            for (int w = 0; w < BLOCK / 64; ++w) tot += sred[r][w];
            logp[row0 + r] = tot + base;
        }
    }
}

extern "C" void kernel_launch(void* const* d_in, const int* in_sizes, int n_in,
                              void* d_out, int out_size, void* d_ws, size_t ws_size,
                              hipStream_t stream) {
    const float* logits = (const float*)d_in[0];
    const float* u      = (const float*)d_in[1];
    const int*   shift  = (const int*)d_in[2];
    const int B = in_sizes[2];

    float* ws    = (float*)d_ws;                    // 2*NB + 1 floats
    float* masks = (float*)d_out;                   // B*NB
    float* logp  = (float*)d_out + (size_t)B * NB;  // B

    fbmp_precompute<<<1, PBLOCK, 0, stream>>>(logits, ws);
    fbmp_main<<<B / ROWS, BLOCK, 0, stream>>>(u, shift, ws, masks, logp);
}

// Round 5
// 253.895 us; speedup vs baseline: 1.0027x; 1.0027x over previous
//
#include <hip/hip_runtime.h>
#include <math.h>
#include <stdint.h>

#define NB 4096
#define PAD 2048
#define BLOCK 256
#define PBLOCK 256
#define NW (NB / 32)   // 128 bit-words per row

__device__ __forceinline__ int mirror_idx(int i) {
    // valid for i in [-PAD, NB+PAD-2]; single reflection
    i = ::abs(i);
    return (i < NB) ? i : (2 * (NB - 1) - i);
}

// Barrier that waits only on LDS ops (lgkmcnt), leaving global loads/stores
// (vmcnt) in flight across the barrier.
__device__ __forceinline__ void lds_barrier() {
    asm volatile("s_waitcnt lgkmcnt(0)\n\ts_barrier" ::: "memory");
}

// ws layout: p[0..NB), d[NB..2NB) = lsp - lsn, ws[2NB] = sum(lsn)
__global__ void fbmp_precompute(const float* __restrict__ logits, float* __restrict__ ws) {
    __shared__ float sred[PBLOCK / 64];
    float lsnsum = 0.0f;
    for (int j = threadIdx.x; j < NB; j += PBLOCK) {
        float x = logits[j];
        double xd = (double)x;
        // p formula bit-matched the reference in rounds 1-4 (absmax 0.0) -- do not touch
        float e = (float)exp(-xd);
        float p = 1.0f / (1.0f + e);
        float lsp = (float)(-log1p(exp(-xd)));  // log_sigmoid(x)
        float lsn = (float)(-log1p(exp(xd)));   // log_sigmoid(-x)
        ws[j] = p;
        ws[NB + j] = lsp - lsn;
        lsnsum += lsn;
    }
    #pragma unroll
    for (int off = 32; off > 0; off >>= 1)
        lsnsum += __shfl_down(lsnsum, off, 64);
    const int lane = threadIdx.x & 63;
    const int wid  = threadIdx.x >> 6;
    if (lane == 0) sred[wid] = lsnsum;
    __syncthreads();
    if (threadIdx.x == 0) {
        float t = 0.0f;
        #pragma unroll
        for (int w = 0; w < PBLOCK / 64; ++w) t += sred[w];
        ws[2 * NB] = t;
    }
}

__global__ __launch_bounds__(BLOCK, 8) void fbmp_main(
    const float* __restrict__ u, const int* __restrict__ shift,
    const float* __restrict__ ws,
    float* __restrict__ masks, float* __restrict__ logp)
{
    __shared__ uint32_t sbits[NW + 2];   // 4096 grid bits + 2 pad words
    __shared__ float sred[BLOCK / 64];

    const int b = blockIdx.x;
    const int t = threadIdx.x;
    const int lane = t & 63;
    const int w = t >> 6;

    const float4* __restrict__ u4 = (const float4*)(u + (size_t)b * NB);
    const float4* __restrict__ p4 = (const float4*)ws;
    const float4* __restrict__ d4 = (const float4*)(ws + NB);
    const int s = shift[b] - PAD;

    // ---- pack: grid bits -> nibbles -> 32-bit words in LDS (linear bit order)
    float acc = 0.0f;
    #pragma unroll
    for (int i = 0; i < 4; ++i) {
        const int f = i * BLOCK + t;      // float4 index; elements 4f..4f+3
        float4 uv = u4[f];
        float4 pv = p4[f];
        float4 dv = d4[f];
        bool c0 = uv.x < pv.x;
        bool c1 = uv.y < pv.y;
        bool c2 = uv.z < pv.z;
        bool c3 = uv.w < pv.w;
        acc += (c0 ? dv.x : 0.0f) + (c1 ? dv.y : 0.0f)
             + (c2 ? dv.z : 0.0f) + (c3 ? dv.w : 0.0f);
        uint32_t n = (c0 ? 1u : 0u) | (c1 ? 2u : 0u) | (c2 ? 4u : 0u) | (c3 ? 8u : 0u);
        // assemble 8 consecutive nibbles (threads t..t+7) into one word
        uint32_t v = n | (((uint32_t)__shfl_xor((int)n, 1, 64)) << 4);
        v |= ((uint32_t)__shfl_xor((int)v, 2, 64)) << 8;
        v |= ((uint32_t)__shfl_xor((int)v, 4, 64)) << 16;
        if ((t & 7) == 0) sbits[i * (BLOCK / 8) + (t >> 3)] = v;  // linear: word f/8
    }

    // logp partial (order changed vs R4 -- tolerance is 56.96, drift ~1e-4)
    #pragma unroll
    for (int off = 32; off > 0; off >>= 1)
        acc += __shfl_down(acc, off, 64);
    if (lane == 0) sred[w] = acc;

    lds_barrier();

    // ---- unpack: each wave-instr emits 256 contiguous outputs (coalesced float4)
    const uint64_t REV4 = 0xF7B3D591E6A2C480ull;  // nibble bit-reverse table
    float4* __restrict__ m4 = (float4*)(masks + (size_t)b * NB);
    #pragma unroll
    for (int i = 0; i < 4; ++i) {
        const int q = 4 * w + i;              // 256-element chunk id
        const int f = 256 * q + 4 * lane + s; // first source index (pre-mirror)
        float4 o;
        if (f >= -3 && f <= 4095 && (f < 0 || f > 4092)) {
            // mixed boundary lane (<=2 per row): per-element fallback
            float* po = &o.x;
            #pragma unroll
            for (int e = 0; e < 4; ++e) {
                int j = mirror_idx(f + e);
                po[e] = (float)((sbits[j >> 5] >> (j & 31)) & 1u);
            }
        } else {
            int sb; bool rev;
            if (f >= 0 && f <= 4092)      { sb = f;        rev = false; }  // interior
            else if (f < 0)               { sb = -f - 3;   rev = true;  }  // left reflect
            else                          { sb = 8187 - f; rev = true;  }  // right reflect
            uint32_t w0 = sbits[sb >> 5];
            uint32_t w1 = sbits[(sb >> 5) + 1];
            uint32_t nib = (uint32_t)((((uint64_t)w1 << 32) | w0) >> (sb & 31)) & 0xFu;
            if (rev) nib = (uint32_t)(REV4 >> (nib << 2)) & 0xFu;
            o.x = (nib & 1u) ? 1.0f : 0.0f;
            o.y = (nib & 2u) ? 1.0f : 0.0f;
            o.z = (nib & 4u) ? 1.0f : 0.0f;
            o.w = (nib & 8u) ? 1.0f : 0.0f;
        }
        m4[q * 64 + lane] = o;
    }

    if (t == 0) {
        float tot = 0.0f;
        #pragma unroll
        for (int ww = 0; ww < BLOCK / 64; ++ww) tot += sred[ww];
        logp[b] = tot + ws[2 * NB];
    }
}

extern "C" void kernel_launch(void* const* d_in, const int* in_sizes, int n_in,
                              void* d_out, int out_size, void* d_ws, size_t ws_size,
                              hipStream_t stream) {
    const float* logits = (const float*)d_in[0];
    const float* u      = (const float*)d_in[1];
    const int*   shift  = (const int*)d_in[2];
    const int B = in_sizes[2];

    float* ws    = (float*)d_ws;                    // 2*NB + 1 floats
    float* masks = (float*)d_out;                   // B*NB
    float* logp  = (float*)d_out + (size_t)B * NB;  // B

    fbmp_precompute<<<1, PBLOCK, 0, stream>>>(logits, ws);
    fbmp_main<<<B, BLOCK, 0, stream>>>(u, shift, ws, masks, logp);
}

// Round 6
// 249.672 us; speedup vs baseline: 1.0197x; 1.0169x over previous
//
#include <hip/hip_runtime.h>
#include <math.h>
#include <stdint.h>

#define NB 4096
#define PAD 2048
#define BLOCK 256
#define NW (NB / 32)   // 128 bit-words per row
#define ROWS 8         // rows per block: amortizes the 32 KB table load
#define NPART 16       // precompute partial-sum blocks

__device__ __forceinline__ int mirror_idx(int i) {
    // valid for i in [-PAD, NB+PAD-2]; single reflection
    i = ::abs(i);
    return (i < NB) ? i : (2 * (NB - 1) - i);
}

// Barrier that waits only on LDS ops (lgkmcnt), leaving global loads/stores
// (vmcnt) in flight across the barrier. The "memory" clobber also pins the
// prefetch loads issued above it.
__device__ __forceinline__ void lds_barrier() {
    asm volatile("s_waitcnt lgkmcnt(0)\n\ts_barrier" ::: "memory");
}

// ws layout: p[0..NB), d[NB..2NB) = lsp - lsn, lsn partials [2NB..2NB+NPART)
// grid = NPART x BLOCK covers NB exactly; deterministic partials (no atomics)
__global__ void fbmp_precompute(const float* __restrict__ logits, float* __restrict__ ws) {
    __shared__ float sred[BLOCK / 64];
    const int j = blockIdx.x * BLOCK + threadIdx.x;
    float x = logits[j];
    double xd = (double)x;
    // p formula bit-matched the reference in rounds 1-5 (absmax 0.0) -- do not touch
    float e = (float)exp(-xd);
    float p = 1.0f / (1.0f + e);
    float lsp = (float)(-log1p(exp(-xd)));  // log_sigmoid(x)
    float lsn = (float)(-log1p(exp(xd)));   // log_sigmoid(-x)
    ws[j] = p;
    ws[NB + j] = lsp - lsn;
    float a = lsn;
    #pragma unroll
    for (int off = 32; off > 0; off >>= 1)
        a += __shfl_down(a, off, 64);
    if ((threadIdx.x & 63) == 0) sred[threadIdx.x >> 6] = a;
    __syncthreads();
    if (threadIdx.x == 0) {
        float t = 0.0f;
        #pragma unroll
        for (int w = 0; w < BLOCK / 64; ++w) t += sred[w];
        ws[2 * NB + blockIdx.x] = t;
    }
}

__global__ __launch_bounds__(BLOCK, 4) void fbmp_main(
    const float* __restrict__ u, const int* __restrict__ shift,
    const float* __restrict__ ws,
    float* __restrict__ masks, float* __restrict__ logp)
{
    __shared__ float s_p[NB];                 // 16 KB: p table (block-lifetime)
    __shared__ float s_d[NB];                 // 16 KB: d table
    __shared__ uint32_t sbits[2][NW + 2];     // double-buffered packed grid bits
    __shared__ float sred[ROWS][BLOCK / 64];

    const int b = blockIdx.x;
    const int t = threadIdx.x;
    const int lane = t & 63;
    const int w = t >> 6;
    const int row0 = b * ROWS;

    // uniform scalar loads: sum of lsn partials (deterministic fixed order)
    float base = 0.0f;
    #pragma unroll
    for (int k = 0; k < NPART; ++k) base += ws[2 * NB + k];

    // ---- tables -> LDS once per block (32 KB; amortized over ROWS rows)
    const float4* __restrict__ p4g = (const float4*)ws;
    const float4* __restrict__ d4g = (const float4*)(ws + NB);
    #pragma unroll
    for (int i = 0; i < 4; ++i) ((float4*)s_p)[i * BLOCK + t] = p4g[i * BLOCK + t];
    #pragma unroll
    for (int i = 0; i < 4; ++i) ((float4*)s_d)[i * BLOCK + t] = d4g[i * BLOCK + t];

    // prologue: row 0 u loads
    float4 ucur[4], unext[4];
    {
        const float4* __restrict__ u0 = (const float4*)(u + (size_t)row0 * NB);
        #pragma unroll
        for (int i = 0; i < 4; ++i) ucur[i] = u0[i * BLOCK + t];
    }
    __syncthreads();  // tables visible (once per block; vmcnt drain acceptable here)

    const uint64_t REV4 = 0xF7B3D591E6A2C480ull;  // nibble bit-reverse table

    for (int r = 0; r < ROWS; ++r) {
        // prefetch next row's u FIRST; stays in flight across the lgkm barrier
        if (r + 1 < ROWS) {
            const float4* __restrict__ un =
                (const float4*)(u + (size_t)(row0 + r + 1) * NB);
            #pragma unroll
            for (int i = 0; i < 4; ++i) unext[i] = un[i * BLOCK + t];
        }
        const int s = shift[row0 + r] - PAD;

        // ---- pack: compare vs p (LDS), acc += d (LDS), bits -> sbits[r&1]
        uint32_t* __restrict__ sbw = sbits[r & 1];
        float acc = 0.0f;
        #pragma unroll
        for (int i = 0; i < 4; ++i) {
            float4 pv = ((const float4*)s_p)[i * BLOCK + t];
            float4 dv = ((const float4*)s_d)[i * BLOCK + t];
            bool c0 = ucur[i].x < pv.x;
            bool c1 = ucur[i].y < pv.y;
            bool c2 = ucur[i].z < pv.z;
            bool c3 = ucur[i].w < pv.w;
            acc += (c0 ? dv.x : 0.0f) + (c1 ? dv.y : 0.0f)
                 + (c2 ? dv.z : 0.0f) + (c3 ? dv.w : 0.0f);
            uint32_t n = (c0 ? 1u : 0u) | (c1 ? 2u : 0u) | (c2 ? 4u : 0u) | (c3 ? 8u : 0u);
            uint32_t v = n | (((uint32_t)__shfl_xor((int)n, 1, 64)) << 4);
            v |= ((uint32_t)__shfl_xor((int)v, 2, 64)) << 8;
            v |= ((uint32_t)__shfl_xor((int)v, 4, 64)) << 16;
            if ((t & 7) == 0) sbw[i * (BLOCK / 8) + (t >> 3)] = v;
        }

        #pragma unroll
        for (int off = 32; off > 0; off >>= 1)
            acc += __shfl_down(acc, off, 64);
        if (lane == 0) sred[r][w] = acc;

        lds_barrier();

        // ---- unpack: reflect-shift from packed bits, coalesced float4 stores
        // (stores remain in flight past the next row's barrier)
        float4* __restrict__ m4 = (float4*)(masks + (size_t)(row0 + r) * NB);
        #pragma unroll
        for (int i = 0; i < 4; ++i) {
            const int q = 4 * w + i;              // 256-element chunk id
            const int f = 256 * q + 4 * lane + s; // first source index (pre-mirror)
            float4 o;
            if (f >= -3 && f <= 4095 && (f < 0 || f > 4092)) {
                // mixed boundary lane (<=2 per row): per-element fallback
                float* po = &o.x;
                #pragma unroll
                for (int e = 0; e < 4; ++e) {
                    int j = mirror_idx(f + e);
                    po[e] = (float)((sbw[j >> 5] >> (j & 31)) & 1u);
                }
            } else {
                int sb; bool rev;
                if (f >= 0 && f <= 4092)      { sb = f;        rev = false; }
                else if (f < 0)               { sb = -f - 3;   rev = true;  }
                else                          { sb = 8187 - f; rev = true;  }
                uint32_t w0 = sbw[sb >> 5];
                uint32_t w1 = sbw[(sb >> 5) + 1];
                uint32_t nib = (uint32_t)((((uint64_t)w1 << 32) | w0) >> (sb & 31)) & 0xFu;
                if (rev) nib = (uint32_t)(REV4 >> (nib << 2)) & 0xFu;
                o.x = (nib & 1u) ? 1.0f : 0.0f;
                o.y = (nib & 2u) ? 1.0f : 0.0f;
                o.z = (nib & 4u) ? 1.0f : 0.0f;
                o.w = (nib & 8u) ? 1.0f : 0.0f;
            }
            m4[q * 64 + lane] = o;
        }

        #pragma unroll
        for (int i = 0; i < 4; ++i) ucur[i] = unext[i];
    }

    // sred writes all precede the final lds_barrier -> visible to t0
    if (t == 0) {
        #pragma unroll
        for (int r = 0; r < ROWS; ++r) {
            float tot = 0.0f;
            #pragma unroll
            for (int ww = 0; ww < BLOCK / 64; ++ww) tot += sred[r][ww];
            logp[row0 + r] = tot + base;
        }
    }
}

extern "C" void kernel_launch(void* const* d_in, const int* in_sizes, int n_in,
                              void* d_out, int out_size, void* d_ws, size_t ws_size,
                              hipStream_t stream) {
    const float* logits = (const float*)d_in[0];
    const float* u      = (const float*)d_in[1];
    const int*   shift  = (const int*)d_in[2];
    const int B = in_sizes[2];

    float* ws    = (float*)d_ws;                    // 2*NB + NPART floats
    float* masks = (float*)d_out;                   // B*NB
    float* logp  = (float*)d_out + (size_t)B * NB;  // B

    fbmp_precompute<<<NPART, BLOCK, 0, stream>>>(logits, ws);
    fbmp_main<<<B / ROWS, BLOCK, 0, stream>>>(u, shift, ws, masks, logp);
}